// Round 8
// baseline (295.290 us; speedup 1.0000x reference)
//
#include <hip/hip_runtime.h>

#define NN 1024
#define DD 64
#define CAP 96
#define RCAP 128
#define SENT 32768   // (1024<<5): <<1 -> u16-index 65536 = -inf dummy G row

typedef __attribute__((ext_vector_type(8))) short bf16x8;
typedef __attribute__((ext_vector_type(4))) float f32x4;

// ---- device-global scratch (rewritten every call) ----
__device__ float    WgTd[128*64];     // WgT[k][d] = Wg[d][k]
__device__ float    WsTd[64*64];      // WsT[k][d] = Ws[d][k]
__device__ float    WnTd[64*64];      // WnT[k][d] = Wn[d][k]
__device__ uint4    WnFragD[8*64];    // MFMA B-fragments: (s*4+t)*64 + lane
__device__ float    FSd[NN*DD];       // inputs @ Ws^T + bs
__device__ float    Gd[NN*DD];        // G0 = h0 @ Wn^T (consumed by k_edges only)
__device__ float    preBaseD[NN*DD];  // inputs@Wg1^T + h0@Wg2^T + bg
__device__ float    fpreD[NN*DD];     // sigmoid(FS + G0)
__device__ float4   nodeDatD[NN*DD];  // {fs, preB2, civ, cf2} per (i,d)
__device__ int      lowNeiD[NN*CAP + 64];  // (j<<5) encoded, SENT-padded everywhere unused
__device__ int      revNeiD[NN*RCAP];
__device__ int      revCntD[NN];
__device__ int2     hdrD[NN];         // {lowCnt(<=64), bits(1/num)}
__device__ int      posArr[NN];
__device__ float    invNumD[NN];

__device__ __forceinline__ float sigm(float x)  { return 1.0f / (1.0f + __expf(-x)); }
__device__ __forceinline__ float tanhf_(float x){ return 2.0f / (1.0f + __expf(-2.0f*x)) - 1.0f; }
__device__ __forceinline__ unsigned short bf16r(float x) {
  unsigned u = __float_as_uint(x);
  u = u + 0x7fffu + ((u >> 16) & 1u);
  return (unsigned short)(u >> 16);
}

// ---- K0: pos[], 1/num, revCnt=0, transposes, MFMA B-frags, sentinel fill ----
__global__ __launch_bounds__(256) void k_prep(const int* __restrict__ seq,
                                              const float* __restrict__ numNei,
                                              const float* __restrict__ Wg,
                                              const float* __restrict__ Ws,
                                              const float* __restrict__ Wn) {
  int gid = blockIdx.x * 256 + threadIdx.x;
  if (gid < NN) { posArr[seq[gid]] = gid; invNumD[gid] = 1.0f / numNei[gid]; revCntD[gid] = 0; }
  if (gid < 512) {  // pack Wn MFMA B-fragments: lane l holds B[8*(l>>4)+j][l&15]
    int st = gid >> 6, lane = gid & 63;
    int s = st >> 2, t = st & 3;
    int row = 16*t + (lane & 15);       // output col index d = 16t + (l&15)
    int k0 = 32*s + 8*(lane >> 4);      // K-slot base (consistent with A staging)
    const float* wr = &Wn[row*64 + k0]; // B[k][d] = WnT[k][d] = Wn[d][k]
    uint4 f;
    f.x = (unsigned)bf16r(wr[0]) | ((unsigned)bf16r(wr[1]) << 16);
    f.y = (unsigned)bf16r(wr[2]) | ((unsigned)bf16r(wr[3]) << 16);
    f.z = (unsigned)bf16r(wr[4]) | ((unsigned)bf16r(wr[5]) << 16);
    f.w = (unsigned)bf16r(wr[6]) | ((unsigned)bf16r(wr[7]) << 16);
    WnFragD[st*64 + lane] = f;
  }
  // sentinel-fill ALL lowNei slots (jb2 reads up to slot 71)
  for (int e = gid; e < NN*CAP; e += 64*256) lowNeiD[e] = SENT;
  if (gid < 128*64) {
    int d = gid >> 7, k = gid & 127;
    WgTd[k*64 + d] = Wg[gid];
  } else if (gid < 128*64 + 64*64) {
    int idx = gid - 128*64; int d = idx >> 6, k = idx & 63;
    WsTd[k*64 + d] = Ws[idx];
  } else {
    int idx = gid - (128*64 + 64*64); int d = idx >> 6, k = idx & 63;
    WnTd[k*64 + d] = Wn[idx];
  }
}

// ---- K1: per-node GEMV precompute (1 wave per node) ----
__global__ __launch_bounds__(256) void k_node(const float* __restrict__ inputs,
                                              const float* __restrict__ h0,
                                              const float* __restrict__ bg,
                                              const float* __restrict__ bs) {
  __shared__ float WsT_l[64*64];
  __shared__ float WnT_l[64*64];
  __shared__ float x_l[4][64];
  __shared__ float hh_l[4][64];
  int tid = threadIdx.x;
  for (int idx = tid; idx < 64*64; idx += 256) { WsT_l[idx] = WsTd[idx]; WnT_l[idx] = WnTd[idx]; }
  int w = tid >> 6, d = tid & 63;
  int i = blockIdx.x * 4 + w;
  x_l[w][d]  = inputs[i*DD + d];
  hh_l[w][d] = h0[i*DD + d];
  __syncthreads();
  float afs = bs[d], apre = bg[d], ag0 = 0.0f;
  #pragma unroll 16
  for (int k = 0; k < 64; ++k) {
    float xk = x_l[w][k], hk = hh_l[w][k];
    afs  += xk * WsT_l[k*64 + d];
    ag0  += hk * WnT_l[k*64 + d];
    apre += xk * WgTd[k*64 + d] + hk * WgTd[(64 + k)*64 + d];
  }
  FSd[i*DD + d]      = afs;
  Gd[i*DD + d]       = ag0;
  preBaseD[i*DD + d] = apre;
  fpreD[i*DD + d]    = sigm(afs + ag0);
}

// ---- K2: split neighbors by position; fold future neighbors; build reverse edges ----
__global__ __launch_bounds__(256) void k_edges(const float* __restrict__ adj,
                                               const float* __restrict__ c0) {
  int tid = threadIdx.x;
  int w = tid >> 6, d = tid & 63;
  int i = blockIdx.x * 4 + w;
  int pi = posArr[i];
  float fs = FSd[i*DD + d];
  float accP = 0.0f, accS = 0.0f;
  int cnt = 0;
  for (int base = 0; base < NN; base += 64) {
    float a = adj[i*NN + base + d];
    unsigned long long mask = __ballot(a != 0.0f);
    while (mask) {
      int b = __ffsll(mask) - 1;
      mask &= (mask - 1);
      int j = base + b;
      if (posArr[j] < pi) {
        if (d == 0 && cnt < 64) {
          lowNeiD[i*CAP + cnt] = j << 5;   // half-encoded u16 row index
          int slot = atomicAdd(&revCntD[j], 1);
          if (slot < RCAP) revNeiD[j*RCAP + slot] = i;
        }
        cnt++;
      } else {
        float g = Gd[j*DD + d];
        accP += g;
        accS += sigm(fs + g);
      }
    }
  }
  float inv = invNumD[i];
  if (d == 0) {
    int ccap = (cnt < 64) ? cnt : 64;
    hdrD[i] = make_int2(ccap, __float_as_int(inv));
  }
  float c0v = c0[i*DD + d];
  float civ = c0v * inv;
  nodeDatD[i*DD + d] = make_float4(fs,
                                   preBaseD[i*DD + d] + accP * inv,
                                   civ,
                                   c0v * fpreD[i*DD + d] + civ * accS);
}

// ---- K3: dataflow scheduler; L2-warm prologue; publish-before-notify ----
__global__ __launch_bounds__(1024, 4) void k_seq(float* __restrict__ out) {
  __shared__ unsigned long long Gl64[(NN*DD + 64)/4];  // bf16 G rows + -inf dummy row
  __shared__ unsigned low8p[NN][4];          // first 8 neighbor codes per node (u16 pairs)
  __shared__ int      queue_[NN];            // packed {node|cnt<<10|rcnt<<17}
  __shared__ int      indeg[NN];             // countdown | cnt<<8 | rcnt<<15
  __shared__ float    invL[NN];
  __shared__ unsigned short hstage[16][64];  // per-wave bf16 h row for MFMA A
  __shared__ int head, tail;
  unsigned short* Gl = (unsigned short*)Gl64;
  int tid  = threadIdx.x;
  int lane = tid & 63, w = tid >> 6;
  if (tid == 0) { head = 0; tail = 0; }
  queue_[tid] = -1;
  int2 hdr = hdrD[tid];
  int  rc  = revCntD[tid];
  int  cnt0 = hdr.x;
  indeg[tid] = cnt0 | (cnt0 << 8) | (rc << 15);
  invL[tid]  = __int_as_float(hdr.y);
  // stage first-8 neighbor codes into LDS (u16-packed)
  {
    uint4 a = *(const uint4*)&lowNeiD[tid*CAP];
    uint4 b = *(const uint4*)&lowNeiD[tid*CAP + 4];
    low8p[tid][0] = (a.x & 0xffffu) | (a.y << 16);
    low8p[tid][1] = (a.z & 0xffffu) | (a.w << 16);
    low8p[tid][2] = (b.x & 0xffffu) | (b.y << 16);
    low8p[tid][3] = (b.z & 0xffffu) | (b.w << 16);
  }
  // -inf dummy row at u16-index 65536 (sentinel pads)
  if (tid < 16) Gl64[NN*DD/4 + tid] = 0xFF80FF80FF80FF80ull;
  // preload Wn MFMA B-fragments: fb[s][t], 32 VGPRs
  uint4 fb[2][4];
  #pragma unroll
  for (int s = 0; s < 2; ++s)
    #pragma unroll
    for (int t = 0; t < 4; ++t)
      fb[s][t] = WnFragD[(s*4 + t)*64 + lane];
  // ---- L2 warm: stream per-node arrays into THIS XCD's L2 (sunk, not DCE-able) ----
  {
    unsigned acc = 0;
    const uint4* pa = (const uint4*)nodeDatD;               // 64k uint4 = 1 MB
    for (int idx = tid; idx < NN*DD; idx += 1024) acc ^= pa[idx].x;
    const uint4* pb = (const uint4*)revNeiD;                // 32k uint4 = 512 KB
    for (int idx = tid; idx < NN*RCAP/4; idx += 1024) acc ^= pb[idx].x;
    const uint4* pc = (const uint4*)lowNeiD;                // 24k uint4 = 384 KB
    for (int idx = tid; idx < NN*CAP/4; idx += 1024) acc ^= pc[idx].x;
    asm volatile("" :: "v"(acc));
  }
  __syncthreads();
  if (cnt0 == 0) {
    int p = __hip_atomic_fetch_add(&tail, 1, __ATOMIC_RELAXED, __HIP_MEMORY_SCOPE_WORKGROUP);
    __hip_atomic_store(&queue_[p], tid | (rc << 17), __ATOMIC_RELEASE, __HIP_MEMORY_SCOPE_WORKGROUP);
  }
  __syncthreads();

  // claim first ticket
  int t0 = 0;
  if (lane == 0) t0 = __hip_atomic_fetch_add(&head, 1, __ATOMIC_RELAXED, __HIP_MEMORY_SCOPE_WORKGROUP);
  int t = __builtin_amdgcn_readfirstlane(t0);

  while (t < NN) {
    __builtin_amdgcn_s_setprio(0);
    int e0 = __hip_atomic_load(&queue_[t], __ATOMIC_ACQUIRE, __HIP_MEMORY_SCOPE_WORKGROUP);
    while (e0 < 0) {
      __builtin_amdgcn_s_sleep(1);
      e0 = __hip_atomic_load(&queue_[t], __ATOMIC_ACQUIRE, __HIP_MEMORY_SCOPE_WORKGROUP);
    }
    __builtin_amdgcn_s_setprio(1);
    int e    = __builtin_amdgcn_readfirstlane(e0);
    int i    = e & 1023;
    int cnt  = (e >> 10) & 127;
    int rcnt = (e >> 17) & 255;
    // issue global + LDS loads up front (all local-L2 hits after the warm)
    float4 nd = nodeDatD[i*DD + lane];
    int jb2 = lowNeiD[i*CAP + 8 + lane];     // slots 8..71 (sentinel beyond cnt)
    int r0 = (lane < rcnt)      ? revNeiD[i*RCAP + lane]      : -1;
    int r1 = (lane + 64 < rcnt) ? revNeiD[i*RCAP + 64 + lane] : -1;
    float inv = invL[i];
    uint4 lv = *(uint4*)&low8p[i][0];        // broadcast 16B: first 8 neighbor codes
    float fs = nd.x;
    float accG = 0.0f, accS = 0.0f;
    {   // batch 0 from LDS codes (starts without waiting on global)
      unsigned v[8] = {lv.x & 0xffffu, lv.x >> 16, lv.y & 0xffffu, lv.y >> 16,
                       lv.z & 0xffffu, lv.z >> 16, lv.w & 0xffffu, lv.w >> 16};
      float g[8];
      #pragma unroll
      for (int q = 0; q < 8; ++q)
        g[q] = __uint_as_float(((unsigned)Gl[(v[q] << 1) + lane]) << 16);
      #pragma unroll
      for (int q = 0; q < 8; ++q) {
        bool valid = q < cnt;
        accG += valid ? g[q] : 0.0f;
        accS += sigm(fs + g[q]);             // pads read -inf -> sigm == 0
      }
    }
    for (int base = 8; base < cnt; base += 8) {
      float g[8];
      #pragma unroll
      for (int q = 0; q < 8; ++q) {
        int jq = __builtin_amdgcn_readlane(jb2, base - 8 + q);
        g[q] = __uint_as_float(((unsigned)Gl[(jq << 1) + lane]) << 16);
      }
      #pragma unroll
      for (int q = 0; q < 8; ++q) {
        bool valid = (base + q) < cnt;
        accG += valid ? g[q] : 0.0f;
        accS += sigm(fs + g[q]);
      }
    }
    float pre = nd.y + inv * accG;
    float is  = sigm(pre);
    float hc  = tanhf_(pre);
    float c   = nd.z * accS + nd.w + is * hc;
    float h   = tanhf_(is * c);
    // claim next ticket early (RMW latency hides under the MFMA tail)
    if (lane == 0) t0 = __hip_atomic_fetch_add(&head, 1, __ATOMIC_RELAXED, __HIP_MEMORY_SCOPE_WORKGROUP);
    t = __builtin_amdgcn_readfirstlane(t0);
    // ---- G[i] = h @ Wn^T on the MFMA pipe; publish BEFORE notify ----
    hstage[w][lane] = bf16r(h);
    const uint4* hv = (const uint4*)&hstage[w][0];
    uint4 fa0 = hv[lane >> 4];        // h[8q .. 8q+7]
    uint4 fa1 = hv[4 + (lane >> 4)];  // h[32+8q .. 32+8q+7]
    f32x4 z = {0.f, 0.f, 0.f, 0.f};
    f32x4 a0 = __builtin_amdgcn_mfma_f32_16x16x32_bf16(__builtin_bit_cast(bf16x8, fa0), __builtin_bit_cast(bf16x8, fb[0][0]), z, 0, 0, 0);
    f32x4 a1 = __builtin_amdgcn_mfma_f32_16x16x32_bf16(__builtin_bit_cast(bf16x8, fa0), __builtin_bit_cast(bf16x8, fb[0][1]), z, 0, 0, 0);
    f32x4 a2 = __builtin_amdgcn_mfma_f32_16x16x32_bf16(__builtin_bit_cast(bf16x8, fa0), __builtin_bit_cast(bf16x8, fb[0][2]), z, 0, 0, 0);
    f32x4 a3 = __builtin_amdgcn_mfma_f32_16x16x32_bf16(__builtin_bit_cast(bf16x8, fa0), __builtin_bit_cast(bf16x8, fb[0][3]), z, 0, 0, 0);
    a0 = __builtin_amdgcn_mfma_f32_16x16x32_bf16(__builtin_bit_cast(bf16x8, fa1), __builtin_bit_cast(bf16x8, fb[1][0]), a0, 0, 0, 0);
    a1 = __builtin_amdgcn_mfma_f32_16x16x32_bf16(__builtin_bit_cast(bf16x8, fa1), __builtin_bit_cast(bf16x8, fb[1][1]), a1, 0, 0, 0);
    a2 = __builtin_amdgcn_mfma_f32_16x16x32_bf16(__builtin_bit_cast(bf16x8, fa1), __builtin_bit_cast(bf16x8, fb[1][2]), a2, 0, 0, 0);
    a3 = __builtin_amdgcn_mfma_f32_16x16x32_bf16(__builtin_bit_cast(bf16x8, fa1), __builtin_bit_cast(bf16x8, fb[1][3]), a3, 0, 0, 0);
    float r01 = (lane & 16) ? a1[0] : a0[0];
    float r23 = (lane & 16) ? a3[0] : a2[0];
    float rg  = (lane & 32) ? r23 : r01;
    Gl[(i << 6) + lane] = bf16r(rg);         // publish data
    // notify dependents (release on RMW orders the Gl write before the push)
    if (r0 >= 0) {
      int old = __hip_atomic_fetch_add(&indeg[r0], -1, __ATOMIC_ACQ_REL, __HIP_MEMORY_SCOPE_WORKGROUP);
      if ((old & 0xff) == 1) {
        int p = __hip_atomic_fetch_add(&tail, 1, __ATOMIC_RELAXED, __HIP_MEMORY_SCOPE_WORKGROUP);
        int en = r0 | (((old >> 8) & 127) << 10) | (((old >> 15) & 255) << 17);
        __hip_atomic_store(&queue_[p], en, __ATOMIC_RELEASE, __HIP_MEMORY_SCOPE_WORKGROUP);
      }
    }
    if (r1 >= 0) {
      int old = __hip_atomic_fetch_add(&indeg[r1], -1, __ATOMIC_ACQ_REL, __HIP_MEMORY_SCOPE_WORKGROUP);
      if ((old & 0xff) == 1) {
        int p = __hip_atomic_fetch_add(&tail, 1, __ATOMIC_RELAXED, __HIP_MEMORY_SCOPE_WORKGROUP);
        int en = r1 | (((old >> 8) & 127) << 10) | (((old >> 15) & 255) << 17);
        __hip_atomic_store(&queue_[p], en, __ATOMIC_RELEASE, __HIP_MEMORY_SCOPE_WORKGROUP);
      }
    }
    // global output store kept OFF the critical notify path
    out[i*DD + lane] = 2.0f * h;
  }
}

extern "C" void kernel_launch(void* const* d_in, const int* in_sizes, int n_in,
                              void* d_out, int out_size, void* d_ws, size_t ws_size,
                              hipStream_t stream) {
  const float* inputs = (const float*)d_in[0];
  const float* adj    = (const float*)d_in[1];
  const float* numNei = (const float*)d_in[2];
  const float* h0     = (const float*)d_in[3];
  const float* c0     = (const float*)d_in[4];
  const float* Wg     = (const float*)d_in[5];
  const float* bg     = (const float*)d_in[6];
  const float* Ws     = (const float*)d_in[7];
  const float* bs     = (const float*)d_in[8];
  const float* Wn     = (const float*)d_in[9];
  const int*   seq    = (const int*)d_in[10];
  float* out = (float*)d_out;

  k_prep <<<64, 256, 0, stream>>>(seq, numNei, Wg, Ws, Wn);
  k_node <<<256, 256, 0, stream>>>(inputs, h0, bg, bs);
  k_edges<<<256, 256, 0, stream>>>(adj, c0);
  k_seq  <<<1, 1024, 0, stream>>>(out);
}

// Round 10
// 208.450 us; speedup vs baseline: 1.4166x; 1.4166x over previous
//
#include <hip/hip_runtime.h>

#define NN 1024
#define DD 64
#define CAP 96
#define RCAP 128
#define SENT 32768   // (1024<<5): decodes to G row 1024 = the ZERO dummy row
#define NL2E -1.44269504088896f

typedef __attribute__((ext_vector_type(8))) short bf16x8;
typedef __attribute__((ext_vector_type(4))) float f32x4;

// ---- device-global scratch (rewritten every call) ----
__device__ float    WgTd[128*64];
__device__ float    WsTd[64*64];
__device__ float    WnTd[64*64];
__device__ uint4    WnFragD[8*64];    // MFMA B-fragments: (s*4+t)*64 + lane
__device__ float    FSd[NN*DD];
__device__ float    Gd[NN*DD];
__device__ float    preBaseD[NN*DD];
__device__ float    fpreD[NN*DD];
__device__ float4   nodeDatD[NN*DD];  // {fs2n, preB2, civ, cf2}
__device__ int      lowNeiD[NN*CAP + 64];  // (j<<5) codes, SENT-padded
__device__ int      revNeiD[NN*RCAP];
__device__ int      revCntD[NN];
__device__ int2     hdrD[NN];
__device__ int      posArr[NN];
__device__ float    invNumD[NN];

__device__ __forceinline__ float sigm(float x)  { return 1.0f / (1.0f + __expf(-x)); }
__device__ __forceinline__ float tanhf_(float x){ return 2.0f / (1.0f + __expf(-2.0f*x)) - 1.0f; }
__device__ __forceinline__ unsigned short bf16r(float x) {
  unsigned u = __float_as_uint(x);
  u = u + 0x7fffu + ((u >> 16) & 1u);
  return (unsigned short)(u >> 16);
}

// ---- K0 ----
__global__ __launch_bounds__(256) void k_prep(const int* __restrict__ seq,
                                              const float* __restrict__ numNei,
                                              const float* __restrict__ Wg,
                                              const float* __restrict__ Ws,
                                              const float* __restrict__ Wn) {
  int gid = blockIdx.x * 256 + threadIdx.x;
  if (gid < NN) { posArr[seq[gid]] = gid; invNumD[gid] = 1.0f / numNei[gid]; revCntD[gid] = 0; }
  if (gid < 512) {
    int st = gid >> 6, lane = gid & 63;
    int s = st >> 2, t = st & 3;
    int row = 16*t + (lane & 15);
    int k0 = 32*s + 8*(lane >> 4);
    const float* wr = &Wn[row*64 + k0];
    uint4 f;
    f.x = (unsigned)bf16r(wr[0]) | ((unsigned)bf16r(wr[1]) << 16);
    f.y = (unsigned)bf16r(wr[2]) | ((unsigned)bf16r(wr[3]) << 16);
    f.z = (unsigned)bf16r(wr[4]) | ((unsigned)bf16r(wr[5]) << 16);
    f.w = (unsigned)bf16r(wr[6]) | ((unsigned)bf16r(wr[7]) << 16);
    WnFragD[st*64 + lane] = f;
  }
  for (int e = gid; e < NN*CAP; e += 64*256) lowNeiD[e] = SENT;
  if (gid < 128*64) {
    int d = gid >> 7, k = gid & 127;
    WgTd[k*64 + d] = Wg[gid];
  } else if (gid < 128*64 + 64*64) {
    int idx = gid - 128*64; int d = idx >> 6, k = idx & 63;
    WsTd[k*64 + d] = Ws[idx];
  } else {
    int idx = gid - (128*64 + 64*64); int d = idx >> 6, k = idx & 63;
    WnTd[k*64 + d] = Wn[idx];
  }
}

// ---- K1 ----
__global__ __launch_bounds__(256) void k_node(const float* __restrict__ inputs,
                                              const float* __restrict__ h0,
                                              const float* __restrict__ bg,
                                              const float* __restrict__ bs) {
  __shared__ float WsT_l[64*64];
  __shared__ float WnT_l[64*64];
  __shared__ float x_l[4][64];
  __shared__ float hh_l[4][64];
  int tid = threadIdx.x;
  for (int idx = tid; idx < 64*64; idx += 256) { WsT_l[idx] = WsTd[idx]; WnT_l[idx] = WnTd[idx]; }
  int w = tid >> 6, d = tid & 63;
  int i = blockIdx.x * 4 + w;
  x_l[w][d]  = inputs[i*DD + d];
  hh_l[w][d] = h0[i*DD + d];
  __syncthreads();
  float afs = bs[d], apre = bg[d], ag0 = 0.0f;
  #pragma unroll 16
  for (int k = 0; k < 64; ++k) {
    float xk = x_l[w][k], hk = hh_l[w][k];
    afs  += xk * WsT_l[k*64 + d];
    ag0  += hk * WnT_l[k*64 + d];
    apre += xk * WgTd[k*64 + d] + hk * WgTd[(64 + k)*64 + d];
  }
  FSd[i*DD + d]      = afs;
  Gd[i*DD + d]       = ag0;
  preBaseD[i*DD + d] = apre;
  fpreD[i*DD + d]    = sigm(afs + ag0);
}

// ---- K2 ----
__global__ __launch_bounds__(256) void k_edges(const float* __restrict__ adj,
                                               const float* __restrict__ c0) {
  int tid = threadIdx.x;
  int w = tid >> 6, d = tid & 63;
  int i = blockIdx.x * 4 + w;
  int pi = posArr[i];
  float fs = FSd[i*DD + d];
  float accP = 0.0f, accS = 0.0f;
  int cnt = 0;
  for (int base = 0; base < NN; base += 64) {
    float a = adj[i*NN + base + d];
    unsigned long long mask = __ballot(a != 0.0f);
    while (mask) {
      int b = __ffsll(mask) - 1;
      mask &= (mask - 1);
      int j = base + b;
      if (posArr[j] < pi) {
        if (d == 0 && cnt < 64) {
          lowNeiD[i*CAP + cnt] = j << 5;
          int slot = atomicAdd(&revCntD[j], 1);
          if (slot < RCAP) revNeiD[j*RCAP + slot] = i;
        }
        cnt++;
      } else {
        float g = Gd[j*DD + d];
        accP += g;
        accS += sigm(fs + g);
      }
    }
  }
  float inv = invNumD[i];
  if (d == 0) {
    int ccap = (cnt < 64) ? cnt : 64;
    hdrD[i] = make_int2(ccap, __float_as_int(inv));
  }
  float c0v = c0[i*DD + d];
  float civ = c0v * inv;
  nodeDatD[i*DD + d] = make_float4(NL2E * fs,                 // fs2n = -fs*log2e
                                   preBaseD[i*DD + d] + accP * inv,
                                   civ,
                                   c0v * fpreD[i*DD + d] + civ * accS);
}

// ---- K3: dataflow scheduler; exp2 gather, zero-pad, pipelined handoff ----
__global__ __launch_bounds__(1024, 4) void k_seq(float* __restrict__ out) {
  __shared__ unsigned long long Gl64[(NN*DD + 64)/4];  // bf16 G rows + ZERO dummy row
  __shared__ unsigned low8p[NN][4];
  __shared__ int      queue_[NN];            // packed {node|cnt<<10|rcnt<<17}
  __shared__ int      indeg[NN];             // countdown | cnt<<8 | rcnt<<15
  __shared__ float    invL[NN];
  __shared__ unsigned short hstage[16][64];
  __shared__ int head, tail;
  unsigned short* Gl = (unsigned short*)Gl64;
  int tid  = threadIdx.x;
  int lane = tid & 63, w = tid >> 6;
  if (tid == 0) { head = 0; tail = 0; }
  queue_[tid] = -1;
  int2 hdr = hdrD[tid];
  int  rc  = revCntD[tid];
  int  cnt0 = hdr.x;
  indeg[tid] = cnt0 | (cnt0 << 8) | (rc << 15);
  invL[tid]  = __int_as_float(hdr.y);
  {
    uint4 a = *(const uint4*)&lowNeiD[tid*CAP];
    uint4 b = *(const uint4*)&lowNeiD[tid*CAP + 4];
    low8p[tid][0] = (a.x & 0xffffu) | (a.y << 16);
    low8p[tid][1] = (a.z & 0xffffu) | (a.w << 16);
    low8p[tid][2] = (b.x & 0xffffu) | (b.y << 16);
    low8p[tid][3] = (b.z & 0xffffu) | (b.w << 16);
  }
  if (tid < 16) Gl64[NN*DD/4 + tid] = 0ull;    // ZERO dummy row
  uint4 fb[2][4];
  #pragma unroll
  for (int s = 0; s < 2; ++s) {
    #pragma unroll
    for (int t = 0; t < 4; ++t)
      fb[s][t] = WnFragD[(s*4 + t)*64 + lane];
  }
  __syncthreads();
  if (cnt0 == 0) {
    int p = __hip_atomic_fetch_add(&tail, 1, __ATOMIC_RELAXED, __HIP_MEMORY_SCOPE_WORKGROUP);
    __hip_atomic_store(&queue_[p], tid | (rc << 17), __ATOMIC_RELEASE, __HIP_MEMORY_SCOPE_WORKGROUP);
  }
  __syncthreads();

  // claim first ticket; blocking pop
  int t0 = 0;
  if (lane == 0) t0 = __hip_atomic_fetch_add(&head, 1, __ATOMIC_RELAXED, __HIP_MEMORY_SCOPE_WORKGROUP);
  int t = __builtin_amdgcn_readfirstlane(t0);
  int e = -1;
  if (t < NN) {
    e = __hip_atomic_load(&queue_[t], __ATOMIC_ACQUIRE, __HIP_MEMORY_SCOPE_WORKGROUP);
    while (e < 0)
      e = __hip_atomic_load(&queue_[t], __ATOMIC_ACQUIRE, __HIP_MEMORY_SCOPE_WORKGROUP);
  } else {
    return;  // never for 16 waves, NN >= 16
  }
  e = __builtin_amdgcn_readfirstlane(e);

  int    i, cnt, rcnt, jb2v, r0, r1;
  float4 nd;
  float  inv;
  uint4  lvv;
  #define ISSUE(E) do {                                               \
    i    = (E) & 1023;                                                \
    cnt  = ((E) >> 10) & 127;                                         \
    rcnt = ((E) >> 17) & 255;                                         \
    nd   = nodeDatD[i*DD + lane];                                     \
    jb2v = lowNeiD[i*CAP + 8 + lane];                                 \
    r0   = (lane < rcnt)      ? revNeiD[i*RCAP + lane]      : -1;     \
    r1   = (lane + 64 < rcnt) ? revNeiD[i*RCAP + 64 + lane] : -1;     \
    inv  = invL[i];                                                   \
    lvv  = *(uint4*)&low8p[i][0];                                     \
  } while (0)
  ISSUE(e);

  for (;;) {
    float fs2n = nd.x;
    float accG = 0.0f, accS = 0.0f;
    // ---- gather: all reads first, then all math ----
    float g0[8], g1[8], g2[8], g3[8];
    #define LD(c) __uint_as_float(((unsigned)Gl[((c) << 1) + lane]) << 16)
    if (cnt > 0) {
      unsigned v0=lvv.x&0xffffu, v1=lvv.x>>16, v2=lvv.y&0xffffu, v3=lvv.y>>16;
      unsigned v4=lvv.z&0xffffu, v5=lvv.z>>16, v6=lvv.w&0xffffu, v7=lvv.w>>16;
      g0[0]=LD(v0); g0[1]=LD(v1); g0[2]=LD(v2); g0[3]=LD(v3);
      g0[4]=LD(v4); g0[5]=LD(v5); g0[6]=LD(v6); g0[7]=LD(v7);
    }
    if (cnt > 8) {
      #pragma unroll
      for (int q = 0; q < 8; ++q) g1[q] = LD(__builtin_amdgcn_readlane(jb2v, q));
    }
    if (cnt > 16) {
      #pragma unroll
      for (int q = 0; q < 8; ++q) g2[q] = LD(__builtin_amdgcn_readlane(jb2v, 8 + q));
    }
    if (cnt > 24) {
      #pragma unroll
      for (int q = 0; q < 8; ++q) g3[q] = LD(__builtin_amdgcn_readlane(jb2v, 16 + q));
    }
    auto domath = [&](float G) {
      float x_ = __builtin_fmaf(G, NL2E, fs2n);
      float e_ = __builtin_amdgcn_exp2f(x_);
      accS += __builtin_amdgcn_rcpf(1.0f + e_);
      accG += G;
    };
    if (cnt > 0) {
      #pragma unroll
      for (int q = 0; q < 8; ++q) domath(g0[q]);
    }
    if (cnt > 8) {
      #pragma unroll
      for (int q = 0; q < 8; ++q) domath(g1[q]);
    }
    if (cnt > 16) {
      #pragma unroll
      for (int q = 0; q < 8; ++q) domath(g2[q]);
    }
    if (cnt > 24) {
      #pragma unroll
      for (int q = 0; q < 8; ++q) domath(g3[q]);
    }
    if (cnt > 32) {
      for (int base = 32; base < cnt; base += 8) {
        float gg[8];
        #pragma unroll
        for (int q = 0; q < 8; ++q) gg[q] = LD(__builtin_amdgcn_readlane(jb2v, base - 8 + q));
        #pragma unroll
        for (int q = 0; q < 8; ++q) domath(gg[q]);
      }
    }
    // pad correction: pads read the zero row -> each added sigm(fs) to accS
    {
      int nb8 = (cnt + 7) & ~7;
      float sig0 = __builtin_amdgcn_rcpf(1.0f + __builtin_amdgcn_exp2f(fs2n));
      accS -= (float)(nb8 - cnt) * sig0;
    }
    float pre = nd.y + inv * accG;
    float is  = sigm(pre);
    float hcl = tanhf_(pre);
    float c   = nd.z * accS + nd.w + is * hcl;
    float h   = tanhf_(is * c);
    // save current node's tail state before ISSUE overwrites
    int ic = i, r0c = r0, r1c = r1;
    // claim next ticket + opportunistic peek/pre-issue (hides under MFMA tail)
    if (lane == 0) t0 = __hip_atomic_fetch_add(&head, 1, __ATOMIC_RELAXED, __HIP_MEMORY_SCOPE_WORKGROUP);
    t = __builtin_amdgcn_readfirstlane(t0);
    bool done = (t >= NN);
    int e2 = -1;
    if (!done) e2 = __hip_atomic_load(&queue_[t], __ATOMIC_ACQUIRE, __HIP_MEMORY_SCOPE_WORKGROUP);
    e2 = __builtin_amdgcn_readfirstlane(e2);
    bool pre_ok = (e2 >= 0);
    if (pre_ok) ISSUE(e2);
    // ---- G[ic] = h @ Wn^T on the MFMA pipe; publish; notify ----
    hstage[w][lane] = bf16r(h);
    const uint4* hv = (const uint4*)&hstage[w][0];
    uint4 fa0 = hv[lane >> 4];
    uint4 fa1 = hv[4 + (lane >> 4)];
    f32x4 z = {0.f, 0.f, 0.f, 0.f};
    f32x4 a0 = __builtin_amdgcn_mfma_f32_16x16x32_bf16(__builtin_bit_cast(bf16x8, fa0), __builtin_bit_cast(bf16x8, fb[0][0]), z, 0, 0, 0);
    f32x4 a1 = __builtin_amdgcn_mfma_f32_16x16x32_bf16(__builtin_bit_cast(bf16x8, fa0), __builtin_bit_cast(bf16x8, fb[0][1]), z, 0, 0, 0);
    f32x4 a2 = __builtin_amdgcn_mfma_f32_16x16x32_bf16(__builtin_bit_cast(bf16x8, fa0), __builtin_bit_cast(bf16x8, fb[0][2]), z, 0, 0, 0);
    f32x4 a3 = __builtin_amdgcn_mfma_f32_16x16x32_bf16(__builtin_bit_cast(bf16x8, fa0), __builtin_bit_cast(bf16x8, fb[0][3]), z, 0, 0, 0);
    a0 = __builtin_amdgcn_mfma_f32_16x16x32_bf16(__builtin_bit_cast(bf16x8, fa1), __builtin_bit_cast(bf16x8, fb[1][0]), a0, 0, 0, 0);
    a1 = __builtin_amdgcn_mfma_f32_16x16x32_bf16(__builtin_bit_cast(bf16x8, fa1), __builtin_bit_cast(bf16x8, fb[1][1]), a1, 0, 0, 0);
    a2 = __builtin_amdgcn_mfma_f32_16x16x32_bf16(__builtin_bit_cast(bf16x8, fa1), __builtin_bit_cast(bf16x8, fb[1][2]), a2, 0, 0, 0);
    a3 = __builtin_amdgcn_mfma_f32_16x16x32_bf16(__builtin_bit_cast(bf16x8, fa1), __builtin_bit_cast(bf16x8, fb[1][3]), a3, 0, 0, 0);
    float r01 = (lane & 16) ? a1[0] : a0[0];
    float r23 = (lane & 16) ? a3[0] : a2[0];
    float rg  = (lane & 32) ? r23 : r01;
    Gl[(ic << 6) + lane] = bf16r(rg);        // publish
    if (r0c >= 0) {
      int old = __hip_atomic_fetch_add(&indeg[r0c], -1, __ATOMIC_ACQ_REL, __HIP_MEMORY_SCOPE_WORKGROUP);
      if ((old & 0xff) == 1) {
        int p = __hip_atomic_fetch_add(&tail, 1, __ATOMIC_RELAXED, __HIP_MEMORY_SCOPE_WORKGROUP);
        int en = r0c | (((old >> 8) & 127) << 10) | (((old >> 15) & 255) << 17);
        __hip_atomic_store(&queue_[p], en, __ATOMIC_RELEASE, __HIP_MEMORY_SCOPE_WORKGROUP);
      }
    }
    if (r1c >= 0) {
      int old = __hip_atomic_fetch_add(&indeg[r1c], -1, __ATOMIC_ACQ_REL, __HIP_MEMORY_SCOPE_WORKGROUP);
      if ((old & 0xff) == 1) {
        int p = __hip_atomic_fetch_add(&tail, 1, __ATOMIC_RELAXED, __HIP_MEMORY_SCOPE_WORKGROUP);
        int en = r1c | (((old >> 8) & 127) << 10) | (((old >> 15) & 255) << 17);
        __hip_atomic_store(&queue_[p], en, __ATOMIC_RELEASE, __HIP_MEMORY_SCOPE_WORKGROUP);
      }
    }
    out[ic*DD + lane] = 2.0f * h;
    if (done) break;
    if (!pre_ok) {
      int e3 = __hip_atomic_load(&queue_[t], __ATOMIC_ACQUIRE, __HIP_MEMORY_SCOPE_WORKGROUP);
      while (e3 < 0)
        e3 = __hip_atomic_load(&queue_[t], __ATOMIC_ACQUIRE, __HIP_MEMORY_SCOPE_WORKGROUP);
      e3 = __builtin_amdgcn_readfirstlane(e3);
      ISSUE(e3);
    }
  }
  #undef LD
  #undef ISSUE
}

extern "C" void kernel_launch(void* const* d_in, const int* in_sizes, int n_in,
                              void* d_out, int out_size, void* d_ws, size_t ws_size,
                              hipStream_t stream) {
  const float* inputs = (const float*)d_in[0];
  const float* adj    = (const float*)d_in[1];
  const float* numNei = (const float*)d_in[2];
  const float* h0     = (const float*)d_in[3];
  const float* c0     = (const float*)d_in[4];
  const float* Wg     = (const float*)d_in[5];
  const float* bg     = (const float*)d_in[6];
  const float* Ws     = (const float*)d_in[7];
  const float* bs     = (const float*)d_in[8];
  const float* Wn     = (const float*)d_in[9];
  const int*   seq    = (const int*)d_in[10];
  float* out = (float*)d_out;

  k_prep <<<64, 256, 0, stream>>>(seq, numNei, Wg, Ws, Wn);
  k_node <<<256, 256, 0, stream>>>(inputs, h0, bg, bs);
  k_edges<<<256, 256, 0, stream>>>(adj, c0);
  k_seq  <<<1, 1024, 0, stream>>>(out);
}